// Round 7
// baseline (4101.340 us; speedup 1.0000x reference)
//
#include <hip/hip_runtime.h>
#include <hip/hip_bf16.h>
#include <cstdint>
#include <cstddef>

// Problem constants: T=512, B=32, I=H=1024, 4H=4096.
#define TSTEPS 512
#define BATCH  32
#define HDIM   1024
#define GDIM   4096
#define NBLK   64   // persistent-kernel grid
#define SPIN_LIMIT (1u << 22)  // bounded spins: convert any protocol bug into
                               // a loud wrong-answer instead of a GPU hang

typedef __attribute__((ext_vector_type(8))) short short8;  // 8 bf16 (4 VGPRs)
typedef __attribute__((ext_vector_type(4))) float f32x4;   // MFMA C/D frag

__device__ __forceinline__ unsigned short f2bf(float f) {
  uint32_t u = __float_as_uint(f);
  uint32_t r = (u + 0x7FFFu + ((u >> 16) & 1u)) >> 16;  // RNE
  return (unsigned short)r;
}

__device__ __forceinline__ void async_ld16(const void* gptr, void* ldsptr) {
  __builtin_amdgcn_global_load_lds(
      (const __attribute__((address_space(1))) void*)gptr,
      (__attribute__((address_space(3))) void*)ldsptr, 16, 0, 0);
}

// ---------------- fp32 -> bf16 conversion (4 elems/thread) ----------------
__global__ void cvt_bf16(const float* __restrict__ s, unsigned short* __restrict__ d, int n4) {
  int i = blockIdx.x * blockDim.x + threadIdx.x;
  if (i < n4) {
    float4 v = ((const float4*)s)[i];
    ushort4 o;
    o.x = f2bf(v.x); o.y = f2bf(v.y); o.z = f2bf(v.z); o.w = f2bf(v.w);
    ((ushort4*)d)[i] = o;
  }
}

// ---- U reorder+convert: Ur[blk*64 + g*16 + j][k] = U[g*1024 + blk*16 + j][k] ----
__global__ void reorder_U(const float* __restrict__ U, unsigned short* __restrict__ Ur) {
  int i = blockIdx.x * blockDim.x + threadIdx.x;  // over 4096*256 float4 groups
  if (i >= GDIM * (HDIM / 4)) return;
  int k4 = i & 255;
  int row_o = i >> 8;
  int blk = row_o >> 6;
  int rem = row_o & 63;
  int g = rem >> 4;
  int jj = rem & 15;
  int src_row = g * HDIM + blk * 16 + jj;
  float4 v = ((const float4*)(U + (size_t)src_row * HDIM))[k4];
  ushort4 o;
  o.x = f2bf(v.x); o.y = f2bf(v.y); o.z = f2bf(v.z); o.w = f2bf(v.w);
  ((ushort4*)(Ur + (size_t)row_o * HDIM))[k4] = o;
}

// ---------------- phase 1: xg = x * W^T + (bias_ih + bias_hh) ----------------
__global__ void __launch_bounds__(256) gemm_xg(
    const unsigned short* __restrict__ A, const unsigned short* __restrict__ Bw,
    const float* __restrict__ bias_ih, const float* __restrict__ bias_hh,
    float* __restrict__ C) {
  __shared__ unsigned short As[128 * 32];  // 8KB
  __shared__ unsigned short Bs[128 * 32];
  const int tid = threadIdx.x;
  const int lane = tid & 63;
  const int wave = tid >> 6;
  const int m0 = blockIdx.x * 128;
  const int n0 = blockIdx.y * 128;
  const int wy = wave >> 1, wx = wave & 1;

  f32x4 acc[4][4] = {};
  const int srow = lane >> 2;
  const int skoff = (lane & 3) * 8;

  for (int k0 = 0; k0 < 1024; k0 += 32) {
    for (int s = 0; s < 2; ++s) {
      int ch = wave * 2 + s;
      int row = ch * 16 + srow;
      async_ld16(A + (size_t)(m0 + row) * 1024 + k0 + skoff, (char*)As + ch * 1024);
      async_ld16(Bw + (size_t)(n0 + row) * 1024 + k0 + skoff, (char*)Bs + ch * 1024);
    }
    __syncthreads();

    const int fr = lane & 15;
    const int fo = (lane >> 4) * 8;
    short8 a[4], b[4];
#pragma unroll
    for (int i = 0; i < 4; ++i)
      a[i] = *(const short8*)(As + (wy * 64 + i * 16 + fr) * 32 + fo);
#pragma unroll
    for (int j = 0; j < 4; ++j)
      b[j] = *(const short8*)(Bs + (wx * 64 + j * 16 + fr) * 32 + fo);
#pragma unroll
    for (int i = 0; i < 4; ++i)
#pragma unroll
      for (int j = 0; j < 4; ++j)
        acc[i][j] = __builtin_amdgcn_mfma_f32_16x16x32_bf16(a[i], b[j], acc[i][j], 0, 0, 0);
    __syncthreads();
  }

  const int fr = lane & 15;
  const int rq = (lane >> 4) * 4;
#pragma unroll
  for (int j = 0; j < 4; ++j) {
    int n = n0 + wx * 64 + j * 16 + fr;
    float bsum = bias_ih[n] + bias_hh[n];
#pragma unroll
    for (int i = 0; i < 4; ++i) {
      int mbase = m0 + wy * 64 + i * 16 + rq;
#pragma unroll
      for (int rr = 0; rr < 4; ++rr)
        C[(size_t)(mbase + rr) * GDIM + n] = acc[i][j][rr] + bsum;
    }
  }
}

// ------- state init: h double-buffer, c, per-block barrier flags -------
// flags MUST be zeroed every call (harness poisons ws with 0xAA, which would
// make every wait pass instantly -> race).
__global__ void init_state(unsigned short* __restrict__ h0, float* __restrict__ c0,
                           unsigned int* __restrict__ flags) {
  int i = blockIdx.x * blockDim.x + threadIdx.x;  // 65536 threads
  if (i < 2 * BATCH * HDIM) h0[i] = 0;
  if (i < BATCH * HDIM) c0[i] = 0.f;
  if (i < NBLK * 32) flags[i] = 0;  // 64 flags, 128B stride each
}

// ---------------- persistent cooperative recurrence ----------------
// 64 blocks x 256 threads. Block blk owns hidden units j = blk*16..+15 (all 4
// gates = 64 Ur rows in VGPRs). Waves are K-slices (256 each).
//
// Round-7 = round-6 schedule with BOUNDED spins (r6 bench died in infra; the
// bound converts any latent protocol bug into a wrong-answer diagnosis).
//
// Schedule: TWO interleaved independent barrier chains over batch halves
// (b 0..15 and b 16..31). Each timestep = two slots:
//   slot (t,hb): [poll chain-hb flags >= 2t+hb-1; one acquire-inv] -> plain h
//   loads -> 32 MFMA -> LDS reduce + gates -> h store (relaxed agent atomic,
//   write-through) -> vmcnt(0)+sync -> post flag = 2t+hb+1 -> out stores ->
//   prefetch next slot's xg.
// The wait for chain hb sits one full slot AFTER its producers posted (the
// other chain's slot runs in between), so flag-propagation latency is hidden
// behind compute instead of serialized with it. All protocol elements
// (store type, drain, relaxed spin, single acquire-inv, plain loads) are
// exactly the r5-proven ones; only the schedule changed.
// Correctness: chains touch disjoint b-ranges; within a chain the wait target
// 2t+hb-1 orders all reads of h_hb(t-1) before any write of h_hb(t+1).
// First slots of a dispatch skip the poll; last slots skip the post.
__global__ void __launch_bounds__(256, 1) lstm_persist(
    const float* __restrict__ xg,            // [Tc*32][4096] chunk
    const unsigned short* __restrict__ Urp,  // [4096][1024] reordered bf16
    unsigned short* __restrict__ hbuf,       // [2][32][1024] bf16
    float* __restrict__ cbuf,                // [32][1024] fp32
    float* __restrict__ out,                 // full output base
    unsigned int* __restrict__ flags,        // [64] stride-32 uints
    int t0, int Tc) {
  __shared__ float partials[4][64][17];  // 17.4 KB (half-batch: 16 cols)
  __shared__ float ex[16][17];           // 1.1 KB h-exchange
  const int tid = threadIdx.x;
  const int lane = tid & 63;
  const int wave = tid >> 6;  // K-slice
  const int blk = blockIdx.x;

  // ---- one-time: U slice -> VGPR A-frags. A[m=lane&15][k=(lane>>4)*8+i] ----
  short8 Af[4][8];  // [gate-tile][k-step] : 128 VGPRs (shared by both chains)
  {
    const int ar = lane & 15;
    const int ak = (lane >> 4) * 8;
#pragma unroll
    for (int mt = 0; mt < 4; ++mt) {
      const unsigned short* base =
          Urp + (size_t)(blk * 64 + mt * 16 + ar) * 1024 + wave * 256 + ak;
#pragma unroll
      for (int s = 0; s < 8; ++s) Af[mt][s] = *(const short8*)(base + s * 32);
    }
  }

  // ---- persistent cell state: thread owns cell (b = hb*16 + b_loc, j = jj) ----
  const int b_loc = tid & 15;  // batch within half
  const int jj = tid >> 4;     // 0..15 hidden unit within block
  float creg[2];
  creg[0] = cbuf[(b_loc) * 1024 + blk * 16 + jj];
  creg[1] = cbuf[(16 + b_loc) * 1024 + blk * 16 + jj];

  // xg prefetch (4 scalars: 4 gates for this thread's cell, one half)
  float xgv[4];
  auto ld_xg = [&](int tl_, int hb_) {
    const float* p = xg + ((size_t)tl_ * 32 + hb_ * 16 + b_loc) * GDIM + blk * 16 + jj;
#pragma unroll
    for (int g = 0; g < 4; ++g) xgv[g] = p[g * 1024];
  };
  ld_xg(0, 0);

  for (int tl = 0; tl < Tc; ++tl) {
#pragma unroll
    for (int hb = 0; hb < 2; ++hb) {
      const int t = t0 + tl;
      const unsigned short* hprev = hbuf + (size_t)(t & 1) * (BATCH * HDIM);
      unsigned short* hnext = hbuf + (size_t)((t + 1) & 1) * (BATCH * HDIM);

      // ---- wait for chain hb's producers (posted one slot ago) ----
      if (tl > 0) {
        if (wave == 0) {
          const unsigned target = (unsigned)(2 * t + hb - 1);
          unsigned spins = 0;
          while (__hip_atomic_load(&flags[lane * 32], __ATOMIC_RELAXED,
                                   __HIP_MEMORY_SCOPE_AGENT) < target) {
            if (++spins > SPIN_LIMIT) break;  // bounded: fail loud, not hang
          }
          __builtin_amdgcn_fence(__ATOMIC_ACQUIRE, "agent");  // one buffer_inv
        }
        __syncthreads();
      }

      // ---- B-frags (h half): plain cached loads (fresh after the inv) ----
      // B[k][n]=h[hb*16+n][k]; n=lane&15, k=wave*256+(lane>>4)*8+s*32
      short8 Bf[8];
      {
        const int kb = wave * 256 + (lane >> 4) * 8;
        const unsigned short* hbp =
            hprev + (size_t)(hb * 16 + (lane & 15)) * 1024 + kb;
#pragma unroll
        for (int s = 0; s < 8; ++s) Bf[s] = *(const short8*)(hbp + s * 32);
      }

      // ---- MFMA: 4 gate-tiles x 1 N-tile x 8 k-steps ----
      f32x4 acc[4] = {};
#pragma unroll
      for (int s = 0; s < 8; ++s)
#pragma unroll
        for (int mt = 0; mt < 4; ++mt)
          acc[mt] = __builtin_amdgcn_mfma_f32_16x16x32_bf16(Af[mt][s], Bf[s], acc[mt], 0, 0, 0);

      // ---- write partials: C/D row=(lane>>4)*4+r, col=lane&15 ----
      {
        const int q4 = (lane >> 4) * 4;
        const int cc = lane & 15;
#pragma unroll
        for (int mt = 0; mt < 4; ++mt)
#pragma unroll
          for (int r = 0; r < 4; ++r)
            partials[wave][mt * 16 + q4 + r][cc] = acc[mt][r];
      }
      __syncthreads();

      // ---- K-reduce + gates; thread owns cell (hb*16+b_loc, jj) ----
      float g[4];
#pragma unroll
      for (int gate = 0; gate < 4; ++gate) {
        const int row = gate * 16 + jj;
        g[gate] = partials[0][row][b_loc] + partials[1][row][b_loc] +
                  partials[2][row][b_loc] + partials[3][row][b_loc] + xgv[gate];
      }
      float it = 1.f / (1.f + __expf(-g[0]));
      float ft = 1.f / (1.f + __expf(-g[1]));
      float ch = tanhf(g[2]);
      float ot = 1.f / (1.f + __expf(-g[3]));
      creg[hb] = ft * creg[hb] + it * ch;
      const float hv = ot * tanhf(creg[hb]);
      ex[b_loc][jj] = hv;
      __syncthreads();

      // ---- h(t+1) half store: coalesced write-through atomics ----
      const bool storer = (tid < 128);
      float v0 = 0.f, v1 = 0.f;
      size_t off = 0;
      if (storer) {
        const int b2 = tid >> 3;  // 0..15
        const int pr = tid & 7;   // jj pair 0..7
        v0 = ex[b2][pr * 2];
        v1 = ex[b2][pr * 2 + 1];
        off = (size_t)(hb * 16 + b2) * 1024 + blk * 16 + pr * 2;
        unsigned int pk = (unsigned)f2bf(v0) | ((unsigned)f2bf(v1) << 16);
        __hip_atomic_store((unsigned int*)(hnext + off), pk, __ATOMIC_RELAXED,
                           __HIP_MEMORY_SCOPE_AGENT);
      }

      // ---- release (r5-proven): drain write-through stores, barrier, post ----
      const bool do_post = (tl + 1 < Tc);
      if (do_post) {
        asm volatile("s_waitcnt vmcnt(0)" ::: "memory");
        __syncthreads();
        if (tid == 0)
          __hip_atomic_store(&flags[blk * 32], (unsigned)(2 * t + hb + 1),
                             __ATOMIC_RELAXED, __HIP_MEMORY_SCOPE_AGENT);
      }

      // ---- out stores: plain coalesced, off every critical path ----
      if (storer) {
        *(float2*)(out + (size_t)t * (BATCH * HDIM) + off) = make_float2(v0, v1);
        if (t == TSTEPS - 1)  // h_n output section
          *(float2*)(out + (size_t)TSTEPS * (BATCH * HDIM) + off) = make_float2(v0, v1);
      }

      // ---- prefetch next slot's xg while the other chain's flags propagate ----
      if (hb == 0) {
        ld_xg(tl, 1);
      } else if (tl + 1 < Tc) {
        ld_xg(tl + 1, 0);
      }
    }
  }

  // ---- persist c (and final c_n output on last chunk) ----
  cbuf[(b_loc) * 1024 + blk * 16 + jj] = creg[0];
  cbuf[(16 + b_loc) * 1024 + blk * 16 + jj] = creg[1];
  if (t0 + Tc == TSTEPS) {
    float* cn = out + (size_t)TSTEPS * (BATCH * HDIM) + (BATCH * HDIM);
    cn[(b_loc) * 1024 + blk * 16 + jj] = creg[0];
    cn[(16 + b_loc) * 1024 + blk * 16 + jj] = creg[1];
  }
}

extern "C" void kernel_launch(void* const* d_in, const int* in_sizes, int n_in,
                              void* d_out, int out_size, void* d_ws, size_t ws_size,
                              hipStream_t stream) {
  const float* x = (const float*)d_in[0];     // [512,32,1024]
  const float* W = (const float*)d_in[1];     // [4096,1024]
  const float* U = (const float*)d_in[2];     // [4096,1024]
  const float* b_ih = (const float*)d_in[3];  // [4096]
  const float* b_hh = (const float*)d_in[4];  // [4096]
  float* out = (float*)d_out;                 // [512,32,1024] ++ [32,1024] ++ [32,1024]

  // ---- workspace layout (ws_size constant across calls -> graph-safe) ----
  char* ws = (char*)d_ws;
  const size_t MB8 = (size_t)8 << 20;
  unsigned short* Wb = (unsigned short*)ws;           // 8 MB bf16 W
  unsigned short* Urp = (unsigned short*)(ws + MB8);  // 8 MB bf16 U reordered
  unsigned short* hbuf = (unsigned short*)(ws + 2 * MB8);      // 2x64KB h double-buffer
  float* cbuf = (float*)(ws + 2 * MB8 + 131072);               // 128KB c
  unsigned int* flags = (unsigned int*)(ws + 2 * MB8 + 262144);  // 64 flags @128B stride
  char* chunkbase = ws + 2 * MB8 + 262144 + 16384;

  const size_t fixed_bytes = 2 * MB8 + 262144 + 16384;
  const size_t per_t = (size_t)BATCH * GDIM * 4 + (size_t)BATCH * HDIM * 2;  // xg + xb
  int Tc = TSTEPS;
  while (Tc > 8 && fixed_bytes + (size_t)Tc * per_t > ws_size) Tc >>= 1;

  unsigned short* xb = (unsigned short*)chunkbase;                  // Tc*32*1024 bf16
  float* xg = (float*)(chunkbase + (size_t)Tc * BATCH * HDIM * 2);  // Tc*32*4096 fp32

  // 1) weights + state init
  cvt_bf16<<<4096, 256, 0, stream>>>(W, Wb, GDIM * HDIM / 4);
  reorder_U<<<4096, 256, 0, stream>>>(U, Urp);
  init_state<<<256, 256, 0, stream>>>(hbuf, cbuf, flags);

  // 2) chunked: cvt x chunk -> GEMM xg chunk -> persistent recurrence chunk
  for (int c0 = 0; c0 < TSTEPS; c0 += Tc) {
    const int Mc = Tc * BATCH;
    cvt_bf16<<<(Mc * HDIM / 4 + 255) / 256, 256, 0, stream>>>(
        x + (size_t)c0 * BATCH * HDIM, xb, Mc * HDIM / 4);
    gemm_xg<<<dim3(Mc / 128, GDIM / 128), 256, 0, stream>>>(xb, Wb, b_ih, b_hh, xg);

    const float* xg_arg = xg;
    const unsigned short* urp_arg = Urp;
    unsigned short* hbuf_arg = hbuf;
    float* cbuf_arg = cbuf;
    float* out_arg = out;
    unsigned int* flags_arg = flags;
    int t0_arg = c0, tc_arg = Tc;
    void* args[] = {&xg_arg, &urp_arg, &hbuf_arg, &cbuf_arg,
                    &out_arg, &flags_arg, &t0_arg, &tc_arg};
    hipLaunchCooperativeKernel((void*)lstm_persist, dim3(NBLK), dim3(256), args, 0, stream);
  }
}

// Round 9
// 3006.134 us; speedup vs baseline: 1.3643x; 1.3643x over previous
//
#include <hip/hip_runtime.h>
#include <hip/hip_bf16.h>
#include <cstdint>
#include <cstddef>

// Problem constants: T=512, B=32, I=H=1024, 4H=4096.
#define TSTEPS 512
#define BATCH  32
#define HDIM   1024
#define GDIM   4096
#define NBLK   64   // persistent-kernel grid
#define SPIN_LIMIT (1u << 22)  // bounded spin (r7-proven harmless): bug -> loud fail

typedef __attribute__((ext_vector_type(8))) short short8;  // 8 bf16 (4 VGPRs)
typedef __attribute__((ext_vector_type(4))) float f32x4;   // MFMA C/D frag

__device__ __forceinline__ unsigned short f2bf(float f) {
  uint32_t u = __float_as_uint(f);
  uint32_t r = (u + 0x7FFFu + ((u >> 16) & 1u)) >> 16;  // RNE
  return (unsigned short)r;
}

// ---- fast gate math: keep transcendentals off the critical path ----
// rcp: ~1ulp hw approx; fine vs bf16 output quantization (~4e-3).
__device__ __forceinline__ float fast_rcp(float x) { return __builtin_amdgcn_rcpf(x); }
__device__ __forceinline__ float fast_sig(float x) {
  return fast_rcp(1.f + __expf(-x));
}
__device__ __forceinline__ float fast_tanh(float x) {
  float xc = fminf(15.f, fmaxf(-15.f, x));  // e^30 finite -> no inf/inf
  float t = __expf(2.f * xc);
  return (t - 1.f) * fast_rcp(t + 1.f);
}

__device__ __forceinline__ void async_ld16(const void* gptr, void* ldsptr) {
  __builtin_amdgcn_global_load_lds(
      (const __attribute__((address_space(1))) void*)gptr,
      (__attribute__((address_space(3))) void*)ldsptr, 16, 0, 0);
}

// ---------------- fp32 -> bf16 conversion (4 elems/thread) ----------------
__global__ void cvt_bf16(const float* __restrict__ s, unsigned short* __restrict__ d, int n4) {
  int i = blockIdx.x * blockDim.x + threadIdx.x;
  if (i < n4) {
    float4 v = ((const float4*)s)[i];
    ushort4 o;
    o.x = f2bf(v.x); o.y = f2bf(v.y); o.z = f2bf(v.z); o.w = f2bf(v.w);
    ((ushort4*)d)[i] = o;
  }
}

// ---- U reorder+convert: Ur[blk*64 + g*16 + j][k] = U[g*1024 + blk*16 + j][k] ----
__global__ void reorder_U(const float* __restrict__ U, unsigned short* __restrict__ Ur) {
  int i = blockIdx.x * blockDim.x + threadIdx.x;  // over 4096*256 float4 groups
  if (i >= GDIM * (HDIM / 4)) return;
  int k4 = i & 255;
  int row_o = i >> 8;
  int blk = row_o >> 6;
  int rem = row_o & 63;
  int g = rem >> 4;
  int jj = rem & 15;
  int src_row = g * HDIM + blk * 16 + jj;
  float4 v = ((const float4*)(U + (size_t)src_row * HDIM))[k4];
  ushort4 o;
  o.x = f2bf(v.x); o.y = f2bf(v.y); o.z = f2bf(v.z); o.w = f2bf(v.w);
  ((ushort4*)(Ur + (size_t)row_o * HDIM))[k4] = o;
}

// ---------------- phase 1: xg = x * W^T + (bias_ih + bias_hh) ----------------
__global__ void __launch_bounds__(256) gemm_xg(
    const unsigned short* __restrict__ A, const unsigned short* __restrict__ Bw,
    const float* __restrict__ bias_ih, const float* __restrict__ bias_hh,
    float* __restrict__ C) {
  __shared__ unsigned short As[128 * 32];  // 8KB
  __shared__ unsigned short Bs[128 * 32];
  const int tid = threadIdx.x;
  const int lane = tid & 63;
  const int wave = tid >> 6;
  const int m0 = blockIdx.x * 128;
  const int n0 = blockIdx.y * 128;
  const int wy = wave >> 1, wx = wave & 1;

  f32x4 acc[4][4] = {};
  const int srow = lane >> 2;
  const int skoff = (lane & 3) * 8;

  for (int k0 = 0; k0 < 1024; k0 += 32) {
    for (int s = 0; s < 2; ++s) {
      int ch = wave * 2 + s;
      int row = ch * 16 + srow;
      async_ld16(A + (size_t)(m0 + row) * 1024 + k0 + skoff, (char*)As + ch * 1024);
      async_ld16(Bw + (size_t)(n0 + row) * 1024 + k0 + skoff, (char*)Bs + ch * 1024);
    }
    __syncthreads();

    const int fr = lane & 15;
    const int fo = (lane >> 4) * 8;
    short8 a[4], b[4];
#pragma unroll
    for (int i = 0; i < 4; ++i)
      a[i] = *(const short8*)(As + (wy * 64 + i * 16 + fr) * 32 + fo);
#pragma unroll
    for (int j = 0; j < 4; ++j)
      b[j] = *(const short8*)(Bs + (wx * 64 + j * 16 + fr) * 32 + fo);
#pragma unroll
    for (int i = 0; i < 4; ++i)
#pragma unroll
      for (int j = 0; j < 4; ++j)
        acc[i][j] = __builtin_amdgcn_mfma_f32_16x16x32_bf16(a[i], b[j], acc[i][j], 0, 0, 0);
    __syncthreads();
  }

  const int fr = lane & 15;
  const int rq = (lane >> 4) * 4;
#pragma unroll
  for (int j = 0; j < 4; ++j) {
    int n = n0 + wx * 64 + j * 16 + fr;
    float bsum = bias_ih[n] + bias_hh[n];
#pragma unroll
    for (int i = 0; i < 4; ++i) {
      int mbase = m0 + wy * 64 + i * 16 + rq;
#pragma unroll
      for (int rr = 0; rr < 4; ++rr)
        C[(size_t)(mbase + rr) * GDIM + n] = acc[i][j][rr] + bsum;
    }
  }
}

// ------- state init: h double-buffer, c, per-block barrier flags -------
// flags MUST be zeroed every call (harness poisons ws with 0xAA, which would
// make every wait pass instantly -> race).
__global__ void init_state(unsigned short* __restrict__ h0, float* __restrict__ c0,
                           unsigned int* __restrict__ flags) {
  int i = blockIdx.x * blockDim.x + threadIdx.x;  // 65536 threads
  if (i < 2 * BATCH * HDIM) h0[i] = 0;
  if (i < BATCH * HDIM) c0[i] = 0.f;
  if (i < NBLK * 32) flags[i] = 0;  // 64 flags, 128B stride each
}

// ---------------- persistent cooperative recurrence ----------------
// 64 blocks x 256 threads. Block blk owns hidden units j = blk*16..+15 (all 4
// gates = 64 Ur rows, held entirely in VGPRs). Waves are K-slices (256 each).
//
// Barrier protocol (r5-PROVEN; do not touch):
//  release: h stores = relaxed-agent atomics (write-through), then explicit
//    s_waitcnt vmcnt(0) + __syncthreads -> tid0 stores flag (no buffer_wbl2;
//    r5 proved vmcnt-ack of write-through atomic stores is a valid release).
//  acquire: wave-0 spins on RELAXED agent flag loads, then ONE fence(acquire)
//    [buffer_inv] so next step's PLAIN cached h loads refetch fresh lines.
//    Plain h loads keep lane-coalescing + per-XCD L2 sharing (atomic h loads
//    cost ~1.6us/step more — r4; sc-flavored loads without a wbl2 producer
//    read stale data — r1/r8).
//  out stores: plain coalesced, after the flag (off the critical path).
//  last step of chunk: skip drain/flag/poll (dispatch boundary publishes).
//
// Round-9 delta: gate math only. Library tanhf (x4/thread) and 4 fp32 full
// divisions were serial VALU on the critical path between acquire and flag
// post; replaced with __expf-based tanh and v_rcp sigmoid (~1e-6 rel err,
// negligible vs bf16 threshold).
__global__ void __launch_bounds__(256, 1) lstm_persist(
    const float* __restrict__ xg,            // [Tc*32][4096] chunk
    const unsigned short* __restrict__ Urp,  // [4096][1024] reordered bf16
    unsigned short* __restrict__ hbuf,       // [2][32][1024] bf16
    float* __restrict__ cbuf,                // [32][1024] fp32
    float* __restrict__ out,                 // full output base
    unsigned int* __restrict__ flags,        // [64] stride-32 uints
    int t0, int Tc) {
  __shared__ float partials[4][64][33];  // 33.8 KB
  __shared__ float ex[32][17];           // 2.2 KB h-exchange (separate: saves a sync)
  const int tid = threadIdx.x;
  const int lane = tid & 63;
  const int wave = tid >> 6;  // K-slice
  const int blk = blockIdx.x;

  // ---- one-time: U slice -> VGPR A-frags. A[m=lane&15][k=(lane>>4)*8+i] ----
  short8 Af[4][8];  // [M-tile][k-step] : 128 VGPRs
  {
    const int ar = lane & 15;
    const int ak = (lane >> 4) * 8;
#pragma unroll
    for (int mt = 0; mt < 4; ++mt) {
      const unsigned short* base =
          Urp + (size_t)(blk * 64 + mt * 16 + ar) * 1024 + wave * 256 + ak;
#pragma unroll
      for (int s = 0; s < 8; ++s) Af[mt][s] = *(const short8*)(base + s * 32);
    }
  }

  // ---- persistent cell state (c) in registers ----
  const int b = tid & 31;    // batch
  const int jjb = tid >> 5;  // 0..7 ; thread owns jj = jjb and jjb+8
  float creg0 = cbuf[b * 1024 + blk * 16 + jjb];
  float creg1 = cbuf[b * 1024 + blk * 16 + jjb + 8];

  // xg prefetch (8 scalars: 4 gates x 2 jj)
  float xgv[8];
  auto ld_xg = [&](int tl) {
    const float* p = xg + ((size_t)tl * 32 + b) * GDIM + blk * 16 + jjb;
#pragma unroll
    for (int g = 0; g < 4; ++g) {
      xgv[g * 2 + 0] = p[g * 1024];
      xgv[g * 2 + 1] = p[g * 1024 + 8];
    }
  };
  ld_xg(0);

  for (int tl = 0; tl < Tc; ++tl) {
    const int t = t0 + tl;
    const unsigned short* hprev = hbuf + (size_t)(t & 1) * (BATCH * HDIM);
    unsigned short* hnext = hbuf + (size_t)((t + 1) & 1) * (BATCH * HDIM);

    // ---- B-frags (h) from global: B[k][n]=h[n][k]; n=lane&15, k=(lane>>4)*8+i
    // Plain cached loads: fresh after the previous step's acquire-inv; 8
    // blocks per XCD share the refetched L2 lines.
    short8 Bf[2][8];
    {
      const int kb = wave * 256 + (lane >> 4) * 8;
#pragma unroll
      for (int nt = 0; nt < 2; ++nt) {
        const unsigned short* hb = hprev + (size_t)(nt * 16 + (lane & 15)) * 1024 + kb;
#pragma unroll
        for (int s = 0; s < 8; ++s) Bf[nt][s] = *(const short8*)(hb + s * 32);
      }
    }

    // ---- MFMA: 4 M-tiles x 2 N-tiles x 8 k-steps ----
    f32x4 acc[4][2] = {};
#pragma unroll
    for (int s = 0; s < 8; ++s)
#pragma unroll
      for (int mt = 0; mt < 4; ++mt)
#pragma unroll
        for (int nt = 0; nt < 2; ++nt)
          acc[mt][nt] =
              __builtin_amdgcn_mfma_f32_16x16x32_bf16(Af[mt][s], Bf[nt][s], acc[mt][nt], 0, 0, 0);

    // ---- write partials: C/D row=(lane>>4)*4+r, col=lane&15 ----
    {
      const int q4 = (lane >> 4) * 4;
      const int cc = lane & 15;
#pragma unroll
      for (int mt = 0; mt < 4; ++mt)
#pragma unroll
        for (int nt = 0; nt < 2; ++nt)
#pragma unroll
          for (int r = 0; r < 4; ++r)
            partials[wave][mt * 16 + q4 + r][nt * 16 + cc] = acc[mt][nt][r];
    }
    __syncthreads();

    // ---- K-reduce + gates; thread owns cells (jjb,b) and (jjb+8,b) ----
    float hv0, hv1;
#pragma unroll
    for (int h2 = 0; h2 < 2; ++h2) {
      const int jj = jjb + 8 * h2;
      float g[4];
#pragma unroll
      for (int gate = 0; gate < 4; ++gate) {
        const int row = gate * 16 + jj;
        g[gate] = partials[0][row][b] + partials[1][row][b] + partials[2][row][b] +
                  partials[3][row][b] + xgv[gate * 2 + h2];
      }
      float it = fast_sig(g[0]);
      float ft = fast_sig(g[1]);
      float ch = fast_tanh(g[2]);
      float ot = fast_sig(g[3]);
      float& cr = h2 ? creg1 : creg0;
      cr = ft * cr + it * ch;
      float hvv = ot * fast_tanh(cr);
      if (h2) hv1 = hvv; else hv0 = hvv;
    }
    ex[b][jjb] = hv0;
    ex[b][jjb + 8] = hv1;
    __syncthreads();

    // ---- h(t+1) store (the only store that must precede the flag) ----
    const int b2 = tid >> 3;  // batch
    const int pr = tid & 7;   // jj pair
    const float v0 = ex[b2][pr * 2];
    const float v1 = ex[b2][pr * 2 + 1];
    const size_t off = (size_t)b2 * 1024 + blk * 16 + pr * 2;
    {
      unsigned int pk = (unsigned)f2bf(v0) | ((unsigned)f2bf(v1) << 16);
      __hip_atomic_store((unsigned int*)(hnext + off), pk, __ATOMIC_RELAXED,
                         __HIP_MEMORY_SCOPE_AGENT);
    }

    const bool not_last = (tl + 1 < Tc);

    // ---- release (r5-proven, NO buffer_wbl2): drain, barrier, flag ----
    if (not_last) {
      asm volatile("s_waitcnt vmcnt(0)" ::: "memory");
      __syncthreads();
      if (tid == 0)
        __hip_atomic_store(&flags[blk * 32], (unsigned)(t + 1), __ATOMIC_RELAXED,
                           __HIP_MEMORY_SCOPE_AGENT);
    }

    // ---- out stores: plain coalesced, off every critical path ----
    {
      *(float2*)(out + (size_t)t * (BATCH * HDIM) + off) = make_float2(v0, v1);
      if (t == TSTEPS - 1)  // h_n output section
        *(float2*)(out + (size_t)TSTEPS * (BATCH * HDIM) + off) = make_float2(v0, v1);
    }

    if (not_last) {
      ld_xg(tl + 1);  // prefetch next xg into registers while waiting
      // ---- acquire: relaxed spin, then ONE invalidate (r5-proven) ----
      if (wave == 0) {
        unsigned spins = 0;
        while (__hip_atomic_load(&flags[lane * 32], __ATOMIC_RELAXED,
                                 __HIP_MEMORY_SCOPE_AGENT) < (unsigned)(t + 1)) {
          if (++spins > SPIN_LIMIT) break;  // bounded: fail loud, not hang
        }
        __builtin_amdgcn_fence(__ATOMIC_ACQUIRE, "agent");  // single buffer_inv
      }
      __syncthreads();
    }
  }

  // ---- persist c (and final c_n output on last chunk) ----
  cbuf[b * 1024 + blk * 16 + jjb] = creg0;
  cbuf[b * 1024 + blk * 16 + jjb + 8] = creg1;
  if (t0 + Tc == TSTEPS) {
    float* cn = out + (size_t)TSTEPS * (BATCH * HDIM) + (BATCH * HDIM);
    cn[b * 1024 + blk * 16 + jjb] = creg0;
    cn[b * 1024 + blk * 16 + jjb + 8] = creg1;
  }
}

extern "C" void kernel_launch(void* const* d_in, const int* in_sizes, int n_in,
                              void* d_out, int out_size, void* d_ws, size_t ws_size,
                              hipStream_t stream) {
  const float* x = (const float*)d_in[0];     // [512,32,1024]
  const float* W = (const float*)d_in[1];     // [4096,1024]
  const float* U = (const float*)d_in[2];     // [4096,1024]
  const float* b_ih = (const float*)d_in[3];  // [4096]
  const float* b_hh = (const float*)d_in[4];  // [4096]
  float* out = (float*)d_out;                 // [512,32,1024] ++ [32,1024] ++ [32,1024]

  // ---- workspace layout (ws_size constant across calls -> graph-safe) ----
  char* ws = (char*)d_ws;
  const size_t MB8 = (size_t)8 << 20;
  unsigned short* Wb = (unsigned short*)ws;           // 8 MB bf16 W
  unsigned short* Urp = (unsigned short*)(ws + MB8);  // 8 MB bf16 U reordered
  unsigned short* hbuf = (unsigned short*)(ws + 2 * MB8);      // 2x64KB h double-buffer
  float* cbuf = (float*)(ws + 2 * MB8 + 131072);               // 128KB c
  unsigned int* flags = (unsigned int*)(ws + 2 * MB8 + 262144);  // 64 flags @128B stride
  char* chunkbase = ws + 2 * MB8 + 262144 + 16384;

  const size_t fixed_bytes = 2 * MB8 + 262144 + 16384;
  const size_t per_t = (size_t)BATCH * GDIM * 4 + (size_t)BATCH * HDIM * 2;  // xg + xb
  int Tc = TSTEPS;
  while (Tc > 8 && fixed_bytes + (size_t)Tc * per_t > ws_size) Tc >>= 1;

  unsigned short* xb = (unsigned short*)chunkbase;                  // Tc*32*1024 bf16
  float* xg = (float*)(chunkbase + (size_t)Tc * BATCH * HDIM * 2);  // Tc*32*4096 fp32

  // 1) weights + state init
  cvt_bf16<<<4096, 256, 0, stream>>>(W, Wb, GDIM * HDIM / 4);
  reorder_U<<<4096, 256, 0, stream>>>(U, Urp);
  init_state<<<256, 256, 0, stream>>>(hbuf, cbuf, flags);

  // 2) chunked: cvt x chunk -> GEMM xg chunk -> persistent recurrence chunk
  for (int c0 = 0; c0 < TSTEPS; c0 += Tc) {
    const int Mc = Tc * BATCH;
    cvt_bf16<<<(Mc * HDIM / 4 + 255) / 256, 256, 0, stream>>>(
        x + (size_t)c0 * BATCH * HDIM, xb, Mc * HDIM / 4);
    gemm_xg<<<dim3(Mc / 128, GDIM / 128), 256, 0, stream>>>(xb, Wb, b_ih, b_hh, xg);

    const float* xg_arg = xg;
    const unsigned short* urp_arg = Urp;
    unsigned short* hbuf_arg = hbuf;
    float* cbuf_arg = cbuf;
    float* out_arg = out;
    unsigned int* flags_arg = flags;
    int t0_arg = c0, tc_arg = Tc;
    void* args[] = {&xg_arg, &urp_arg, &hbuf_arg, &cbuf_arg,
                    &out_arg, &flags_arg, &t0_arg, &tc_arg};
    hipLaunchCooperativeKernel((void*)lstm_persist, dim3(NBLK), dim3(256), args, 0, stream);
  }
}